// Round 5
// baseline (86441.754 us; speedup 1.0000x reference)
//
#include <hip/hip_runtime.h>

// =====================================================================
// AutoregressiveSubsetSampler — persistent cooperative kernel, MI355X.
// Round 5: de-serialize the reductions.
//  * px/h/pg: 8 GROUP accumulators (WG b -> group b>>3): fp64 atomic
//    chain depth 64 -> 8; readers sum the 8 slots in fixed order
//    (bitwise-identical across WGs -> redundant LN stays consistent).
//  * counts: NO atomics (was a 128-deep u32 RMW chain on 4 addresses).
//    Each WG stores its 4 per-attempt 32-bit masks to its own slot;
//    stage C: each WG popc+shuffle-reduces all 64 masks per attempt.
//  * poll loop: s_sleep(1) between relaxed polls (don't hammer the
//    flag lines while late WGs try to store to them).
// Structure unchanged from R4: 64 WGs x 256 thr, 2 barriers/step,
// fp64 everywhere on the logit chain, weights in VGPRs.
// =====================================================================

typedef unsigned int u32;

#define NWG   64
#define NT    256
#define NSTEP 8192

// ---- relaxed agent-scope (LLC-direct, cache-bypassing) ops ----
__device__ __forceinline__ double gld(const double* p) {
  return __hip_atomic_load(p, __ATOMIC_RELAXED, __HIP_MEMORY_SCOPE_AGENT);
}
__device__ __forceinline__ void gst(double* p, double v) {
  __hip_atomic_store(p, v, __ATOMIC_RELAXED, __HIP_MEMORY_SCOPE_AGENT);
}
__device__ __forceinline__ u32 gldu(const u32* p) {
  return __hip_atomic_load(p, __ATOMIC_RELAXED, __HIP_MEMORY_SCOPE_AGENT);
}
__device__ __forceinline__ void gstu(u32* p, u32 v) {
  __hip_atomic_store(p, v, __ATOMIC_RELAXED, __HIP_MEMORY_SCOPE_AGENT);
}
__device__ __forceinline__ void gstf(float* p, float v) {
  __hip_atomic_store(p, v, __ATOMIC_RELAXED, __HIP_MEMORY_SCOPE_AGENT);
}
// fp64 atomic add -> global_atomic_add_f64 (HW instr on gfx950)
__device__ __forceinline__ void gadd(double* p, double v) {
  unsafeAtomicAdd(p, v);
}

// ---- flag-array grid barrier: 64 contiguous u32 slots (2 cachelines).
// __syncthreads drains each wave's vmcnt before s_barrier, so all of the
// WG's global stores/atomics are LLC-acked before lane 0 raises its flag.
__device__ __forceinline__ void gbar(u32* flags, u32 e) {
  __syncthreads();
  if (threadIdx.x == 0) gstu(&flags[blockIdx.x], e);
  if (threadIdx.x < 64) {
    while (gldu(&flags[threadIdx.x]) < e) { __builtin_amdgcn_s_sleep(1); }
  }
  asm volatile("" ::: "memory");
  __syncthreads();
}

// block-wide sum of one double per thread (deterministic order per WG;
// redundant WGs execute identical sequences -> bitwise-identical results)
__device__ __forceinline__ double block_sum(double v, double* sred) {
  #pragma unroll
  for (int off = 32; off; off >>= 1) v += __shfl_down(v, off);
  __syncthreads();
  if ((threadIdx.x & 63) == 0) sred[threadIdx.x >> 6] = v;
  __syncthreads();
  return sred[0] + sred[1] + sred[2] + sred[3];
}

// ---------------------------------------------------------------------
// prep kernels (every launch; ~100us, fp64)
// ---------------------------------------------------------------------
__global__ void prep_zero(u32* hdr) {
  int i = blockIdx.x * 256 + threadIdx.x;
  if (i < 25600) hdr[i] = 0u;   // 4KB hdr (flags+masks) + 96KB accumulators
}

// Wg2 = Wg @ W2   [256x512];  c1 = Wg@b2 + bg
__global__ __launch_bounds__(256) void prep_mm1(const float* __restrict__ Wg,
    const float* __restrict__ W2, const float* __restrict__ b2,
    const float* __restrict__ bg, double* __restrict__ Wg2d, double* __restrict__ c1d) {
  int i = threadIdx.x, j = blockIdx.x;
  double acc = 0.0;
  for (int k = 0; k < 256; k++) acc += (double)Wg[i * 256 + k] * (double)W2[k * 512 + j];
  Wg2d[(size_t)i * 512 + j] = acc;
  if (j == 0) {
    double c = 0.0;
    for (int k = 0; k < 256; k++) c += (double)Wg[i * 256 + k] * (double)b2[k];
    c1d[i] = c + (double)bg[i];
  }
}

// Wov = Wo @ Wv  [256x256];  c2 = Wo@bv + bo
__global__ __launch_bounds__(256) void prep_mm2(const float* __restrict__ Wo,
    const float* __restrict__ Wv, const float* __restrict__ bv,
    const float* __restrict__ bo, double* __restrict__ Wovd, double* __restrict__ c2d) {
  int i = threadIdx.x, j = blockIdx.x;
  double acc = 0.0;
  for (int k = 0; k < 256; k++) acc += (double)Wo[i * 256 + k] * (double)Wv[k * 256 + j];
  Wovd[i * 256 + j] = acc;
  if (j == 0) {
    double c = 0.0;
    for (int k = 0; k < 256; k++) c += (double)Wo[i * 256 + k] * (double)bv[k];
    c2d[i] = c + (double)bo[i];
  }
}

// Awg = (I + Wov) @ Wg2  [256x512];  c3 = (I+Wov)@c1 + c2
__global__ __launch_bounds__(256) void prep_mm3(const double* __restrict__ Wg2d,
    const double* __restrict__ Wovd, const double* __restrict__ c1d,
    const double* __restrict__ c2d, double* __restrict__ Awgd, double* __restrict__ c3d) {
  int i = threadIdx.x, j = blockIdx.x;
  double acc = Wg2d[(size_t)i * 512 + j];
  for (int k = 0; k < 256; k++) acc += Wovd[i * 256 + k] * Wg2d[(size_t)k * 512 + j];
  Awgd[(size_t)i * 512 + j] = acc;
  if (j == 0) {
    double c = c1d[i] + c2d[i];
    for (int k = 0; k < 256; k++) c += Wovd[i * 256 + k] * c1d[k];
    c3d[i] = c;
  }
}

// ---------------------------------------------------------------------
// main persistent kernel: 64 WGs x 256 threads, 8192 steps, 2 barriers/step
// ---------------------------------------------------------------------
__global__ __launch_bounds__(256) void sampler_main(
    const float* __restrict__ gnn, const float* __restrict__ u,
    const float* __restrict__ W1, const float* __restrict__ b1,
    const float* __restrict__ W2, const float* __restrict__ b2,
    const float* __restrict__ Wr, const float* __restrict__ br,
    const float* __restrict__ Wf1, const float* __restrict__ bf1,
    const float* __restrict__ Wf2, const float* __restrict__ bf2,
    const float* __restrict__ ln1g, const float* __restrict__ ln1b,
    const float* __restrict__ ln2g, const float* __restrict__ ln2b,
    const double* __restrict__ Awgd, const double* __restrict__ c3d,
    double* __restrict__ pxbuf, double* __restrict__ hbuf,
    double* __restrict__ pgbuf, u32* __restrict__ hdr,
    float* __restrict__ out) {

  __shared__ double smg[512];        // [ m_t ; g ]
  __shared__ double sh1[8];          // local h1 slice
  __shared__ double sx [256];        // x = ln1(px)
  __shared__ double shh[256];        // h broadcast
  __shared__ double sf1[32];         // local f1 slice
  __shared__ double sprob[32];
  __shared__ double sred[8];
  __shared__ u32 ssamp[4];
  __shared__ u32 scnt[4];
  __shared__ int sidx;

  const int b = blockIdx.x, tid = threadIdx.x;
  const int grp = b >> 3;            // 8 groups of 8 WGs
  u32* flags = hdr;                  // 64 contiguous u32
  u32* samp  = hdr + 256;            // [4][64] u32 per-WG attempt masks

  // ---- per-thread weight slices -> registers ----
  const int r1 = tid >> 5, l1 = tid & 31;     // stage A: W1 row 8b+r1
  float w1reg[16];
  #pragma unroll
  for (int k = 0; k < 16; k++) w1reg[k] = W1[(size_t)(8 * b + r1) * 512 + l1 + 32 * k];

  // K-col slices: this thread owns OUTPUT index tid, K-cols 8b..8b+8
  double areg[8]; float w2reg[8];
  #pragma unroll
  for (int k = 0; k < 8; k++) {
    areg[k]  = Awgd[(size_t)tid * 512 + 8 * b + k];
    w2reg[k] = W2  [(size_t)tid * 512 + 8 * b + k];
  }
  const int r3 = tid >> 3, l3 = tid & 7;      // stage B: rows 32b+r3
  float f1reg[32], wrreg[32];
  #pragma unroll
  for (int k = 0; k < 32; k++) {
    f1reg[k] = Wf1[(size_t)(32 * b + r3) * 256 + l3 + 8 * k];
    wrreg[k] = Wr [(size_t)(32 * b + r3) * 256 + l3 + 8 * k];
  }
  // Wf2 K-col slice: output tid, K-cols 32b..32b+32
  float f2reg[32];
  #pragma unroll
  for (int k = 0; k < 32; k++) f2reg[k] = Wf2[(size_t)tid * 2048 + 32 * b + k];

  // per-thread constants
  const double ln1gv = (double)ln1g[tid], ln1bv = (double)ln1b[tid];
  const double ln2gv = (double)ln2g[tid], ln2bv = (double)ln2b[tid];
  const double b1v  = (double)b1 [8 * b + r1];
  const double b2v  = (double)b2 [tid];
  const double c3v  =          c3d[tid];
  const double bf1v = (double)bf1[32 * b + r3];
  const double brv  = (double)br [32 * b + r3];
  const double bf2v = (double)bf2[tid];

  // initial state: m(0) = gnn row 0, g0 = 0
  smg[tid]       = (double)gnn[tid];
  smg[256 + tid] = 0.0;
  __syncthreads();

  for (int t = 0; t < NSTEP; ++t) {
    const int p = t & 1;
    double* pxp = pxbuf + p * 2048;   // [8][256] this parity
    double* hp_ = hbuf  + p * 2048;
    double* pgp = pgbuf + p * 2048;

    // ================= stage A =================
    float ureg = 0.0f;                          // u(t) prefetch (used stage B)
    if (tid < 128)
      ureg = u[((size_t)t * 4 + (tid >> 5)) * 2048 + 32 * b + (tid & 31)];
    {
      double acc = 0.0;                         // h1 slice, rows 8b..8b+7
      #pragma unroll
      for (int k = 0; k < 16; k++) acc += (double)w1reg[k] * smg[l1 + 32 * k];
      #pragma unroll
      for (int off = 16; off; off >>= 1) acc += __shfl_down(acc, off, 32);
      if (l1 == 0) { double v = acc + b1v; sh1[r1] = (v > 0.0) ? v : 0.0; }
    }
    __syncthreads();
    {
      double pxv = 0.0, hv = 0.0;               // K-partials for px, h
      #pragma unroll
      for (int k = 0; k < 8; k++) {
        double h1k = sh1[k];
        pxv += areg[k] * h1k; hv += (double)w2reg[k] * h1k;
      }
      if (b == 0) { pxv += c3v; hv += b2v; }
      gadd(&pxp[grp * 256 + tid], pxv);         // depth-8 chain per address
      gadd(&hp_[grp * 256 + tid], hv);
    }
    gbar(flags, 2 * t + 1);   // B1: px, h group-slots complete

    // ================= stage B =================
    double pxv, hv;
    {
      double tpx[8], th[8];
      #pragma unroll
      for (int g = 0; g < 8; g++) { tpx[g] = gld(&pxp[g * 256 + tid]); th[g] = gld(&hp_[g * 256 + tid]); }
      pxv = 0.0; hv = 0.0;
      #pragma unroll
      for (int g = 0; g < 8; g++) { pxv += tpx[g]; hv += th[g]; }   // fixed order
    }
    double mnext = (double)gnn[(size_t)((t + 1) & 4095) * 256 + tid];
    shh[tid] = hv;
    double xv;
    {
      double mu  = block_sum(pxv, sred) * (1.0 / 256.0);
      double dv  = pxv - mu;
      double var = block_sum(dv * dv, sred) * (1.0 / 256.0);
      xv = dv * (1.0 / sqrt(var + 1e-5)) * ln1gv + ln1bv;
    }
    sx[tid]  = xv;
    smg[tid] = mnext;                            // m(t+1)
    __syncthreads();
    {
      double accF = 0.0, accL = 0.0;             // f1 rows + logit rows 32b+r3
      #pragma unroll
      for (int k = 0; k < 32; k++) {
        int j = l3 + 8 * k;
        accF += (double)f1reg[k] * sx[j];
        accL += (double)wrreg[k] * shh[j];
      }
      #pragma unroll
      for (int off = 4; off; off >>= 1) { accF += __shfl_down(accF, off, 8); accL += __shfl_down(accL, off, 8); }
      if (l3 == 0) {
        double fv = accF + bf1v;
        sf1[r3]   = (fv > 0.0) ? fv : 0.0;
        sprob[r3] = 1.0 / (1.0 + exp(-(accL + brv)));
      }
    }
    __syncthreads();
    if (tid < 128) {                             // masks -> own slot, NO atomics
      int a = tid >> 5;
      bool pred = ((double)ureg < sprob[tid & 31]);
      unsigned long long bal = __ballot(pred);
      int l64 = tid & 63;
      if (l64 == 0) {
        u32 mm = (u32)(bal & 0xffffffffull);
        ssamp[a] = mm; gstu(&samp[a * 64 + b], mm);
      } else if (l64 == 32) {
        u32 mm = (u32)(bal >> 32);
        ssamp[a] = mm; gstu(&samp[a * 64 + b], mm);
      }
    }
    {
      double pgv = 0.0;                          // pg K-partial
      #pragma unroll
      for (int k = 0; k < 32; k++) pgv += (double)f2reg[k] * sf1[k];
      if (b == 0) pgv += xv + bf2v;
      gadd(&pgp[grp * 256 + tid], pgv);
    }
    if (b >= 8 && b < 16) {                      // zero next-parity group b-8
      int g = b - 8;
      gst(&pxbuf[(1 - p) * 2048 + g * 256 + tid], 0.0);
      gst(&hbuf [(1 - p) * 2048 + g * 256 + tid], 0.0);
      gst(&pgbuf[(1 - p) * 2048 + g * 256 + tid], 0.0);
    }
    gbar(flags, 2 * t + 2);   // B2: pg slots, masks complete

    // ================= stage C =================
    u32 cc;                                      // exact counts from masks
    {
      int a = tid >> 6, w = tid & 63;
      cc = (u32)__popc(gldu(&samp[a * 64 + w]));
      #pragma unroll
      for (int off = 32; off; off >>= 1) cc += __shfl_down(cc, off);
    }
    double pgv;
    {
      double tpg[8];
      #pragma unroll
      for (int g = 0; g < 8; g++) tpg[g] = gld(&pgp[g * 256 + tid]);
      pgv = 0.0;
      #pragma unroll
      for (int g = 0; g < 8; g++) pgv += tpg[g];
    }
    if ((tid & 63) == 0) scnt[tid >> 6] = cc;
    __syncthreads();
    if (tid == 0) {
      int idx = 0;
      for (int a = 3; a >= 0; a--) {
        u32 c = scnt[a];
        if (c == 0u || (c >= 2u && c <= 6u)) idx = a;
      }
      sidx = idx;
    }
    {
      double mu  = block_sum(pgv, sred) * (1.0 / 256.0);
      double dv  = pgv - mu;
      double var = block_sum(dv * dv, sred) * (1.0 / 256.0);
      smg[256 + tid] = dv * (1.0 / sqrt(var + 1e-5)) * ln2gv + ln2bv;
    }
    __syncthreads();
    if (tid < 32) {
      u32 mm = ssamp[sidx];
      gstf(&out[(size_t)t * 2048 + 32 * b + tid], ((mm >> tid) & 1u) ? 1.0f : 0.0f);
    }
  }
}

// ---------------------------------------------------------------------
extern "C" void kernel_launch(void* const* d_in, const int* in_sizes, int n_in,
                              void* d_out, int out_size, void* d_ws, size_t ws_size,
                              hipStream_t stream) {
  const float* gnn = (const float*)d_in[0];
  const float* u   = (const float*)d_in[2];
  const float* W1  = (const float*)d_in[3];
  const float* b1  = (const float*)d_in[4];
  const float* W2  = (const float*)d_in[5];
  const float* b2  = (const float*)d_in[6];
  const float* Wr  = (const float*)d_in[7];
  const float* br  = (const float*)d_in[8];
  const float* Wg  = (const float*)d_in[9];
  const float* bg  = (const float*)d_in[10];
  const float* Wv  = (const float*)d_in[11];
  const float* bv  = (const float*)d_in[12];
  const float* Wo  = (const float*)d_in[13];
  const float* bo  = (const float*)d_in[14];
  const float* Wf1 = (const float*)d_in[15];
  const float* bf1 = (const float*)d_in[16];
  const float* Wf2 = (const float*)d_in[17];
  const float* bf2 = (const float*)d_in[18];
  const float* ln1g = (const float*)d_in[19];
  const float* ln1b = (const float*)d_in[20];
  const float* ln2g = (const float*)d_in[21];
  const float* ln2b = (const float*)d_in[22];
  float* out = (float*)d_out;

  // workspace: [0,4KB) flags+mask slots; [4KB,100KB) group accumulators
  u32* hdr = (u32*)d_ws;
  double* pxbuf = (double*)((char*)d_ws + 4096);   // [2][8][256]
  double* hbuf  = pxbuf + 4096;                    // [2][8][256]
  double* pgbuf = hbuf  + 4096;                    // [2][8][256]
  double* base  = (double*)((char*)d_ws + 112 * 1024);
  double* c1d   = base;            // 256
  double* c2d   = c1d + 256;       // 256
  double* c3d   = c2d + 256;       // 256
  double* Wg2d  = c3d + 256;       // 131072
  double* Wovd  = Wg2d + 131072;   // 65536
  double* Awgd  = Wovd + 65536;    // 131072

  hipLaunchKernelGGL(prep_zero, dim3(100), dim3(256), 0, stream, hdr);
  hipLaunchKernelGGL(prep_mm1, dim3(512), dim3(256), 0, stream, Wg, W2, b2, bg, Wg2d, c1d);
  hipLaunchKernelGGL(prep_mm2, dim3(256), dim3(256), 0, stream, Wo, Wv, bv, bo, Wovd, c2d);
  hipLaunchKernelGGL(prep_mm3, dim3(512), dim3(256), 0, stream, Wg2d, Wovd, c1d, c2d, Awgd, c3d);
  hipLaunchKernelGGL(sampler_main, dim3(NWG), dim3(NT), 0, stream,
                     gnn, u, W1, b1, W2, b2, Wr, br, Wf1, bf1, Wf2, bf2,
                     ln1g, ln1b, ln2g, ln2b, Awgd, c3d,
                     pxbuf, hbuf, pgbuf, hdr, out);
}